// Round 6
// baseline (989.663 us; speedup 1.0000x reference)
//
#include <hip/hip_runtime.h>

// Problem constants (B=16, N=4096, C=64, O=64, D=16, K=3)
#define NN 4096
#define DD 16
#define BB 16
#define CC 64
#define OO 64
#define BC 1024   // BB*CC

typedef unsigned short u16;
typedef __attribute__((ext_vector_type(8))) short bf16x8;
typedef __attribute__((ext_vector_type(4))) float f32x4;

__device__ __forceinline__ u16 f2bf(float f) {
    unsigned u = __builtin_bit_cast(unsigned, f);
    unsigned r = u + 0x7FFFu + ((u >> 16) & 1u);
    return (u16)(r >> 16);
}
__device__ __forceinline__ float bf2f(u16 h) {
    unsigned u = ((unsigned)h) << 16;
    return __builtin_bit_cast(float, u);
}

// ---------------------------------------------------------------------------
// Kernel 1: A = softmax(relu(E @ E^T), axis=1) -> split bf16 (Ah + Al)
// ---------------------------------------------------------------------------
__global__ __launch_bounds__(256) void softmax_adj(const float* __restrict__ E,
                                                   u16* __restrict__ Ah,
                                                   u16* __restrict__ Al) {
    const int i = blockIdx.x;
    const int t = threadIdx.x;
    __shared__ float esh[DD];
    __shared__ float redm[4], reds[4];
    if (t < DD) esh[t] = E[i * DD + t];
    __syncthreads();
    float er[DD];
#pragma unroll
    for (int d = 0; d < DD; ++d) er[d] = esh[d];

    float v[16];
    float m = 0.0f;  // relu => max >= 0
#pragma unroll
    for (int s = 0; s < 16; ++s) {
        const int j = s * 256 + t;
        const float4* ej = (const float4*)(E + j * DD);
        float4 a0 = ej[0], a1 = ej[1], a2 = ej[2], a3 = ej[3];
        float dot = a0.x * er[0] + a0.y * er[1] + a0.z * er[2] + a0.w * er[3]
                  + a1.x * er[4] + a1.y * er[5] + a1.z * er[6] + a1.w * er[7]
                  + a2.x * er[8] + a2.y * er[9] + a2.z * er[10] + a2.w * er[11]
                  + a3.x * er[12] + a3.y * er[13] + a3.z * er[14] + a3.w * er[15];
        v[s] = fmaxf(dot, 0.0f);
        m = fmaxf(m, v[s]);
    }
#pragma unroll
    for (int off = 1; off < 64; off <<= 1) m = fmaxf(m, __shfl_xor(m, off));
    const int wave = t >> 6, lane = t & 63;
    if (lane == 0) redm[wave] = m;
    __syncthreads();
    m = fmaxf(fmaxf(redm[0], redm[1]), fmaxf(redm[2], redm[3]));

    float sum = 0.0f;
#pragma unroll
    for (int s = 0; s < 16; ++s) {
        v[s] = expf(v[s] - m);
        sum += v[s];
    }
#pragma unroll
    for (int off = 1; off < 64; off <<= 1) sum += __shfl_xor(sum, off);
    if (lane == 0) reds[wave] = sum;
    __syncthreads();
    const float rinv = 1.0f / (reds[0] + reds[1] + reds[2] + reds[3]);
#pragma unroll
    for (int s = 0; s < 16; ++s) {
        const float val = v[s] * rinv;
        const u16 hh = f2bf(val);
        Ah[(size_t)i * NN + s * 256 + t] = hh;
        Al[(size_t)i * NN + s * 256 + t] = f2bf(val - bf2f(hh));
    }
}

// ---------------------------------------------------------------------------
// Kernel 2: transpose+split X [B,N,C] -> Xt_{h,l} [BC=b*64+c][N] bf16
// ---------------------------------------------------------------------------
__global__ __launch_bounds__(256) void pack_xt(const float* __restrict__ X,
                                               u16* __restrict__ Xth,
                                               u16* __restrict__ Xtl) {
    const int n0 = blockIdx.x * 64;
    const int b  = blockIdx.y;
    const int t  = threadIdx.x;
    __shared__ float tx[64][68];
    const float* src = X + (size_t)b * (NN * CC) + (size_t)n0 * CC;
#pragma unroll
    for (int l = 0; l < 4; ++l) {
        const int idx = t + l * 256;   // 1024 float4 chunks
        const int r = idx >> 4;
        const int c4 = (idx & 15) * 4;
        float4 v = *(const float4*)(src + r * CC + c4);
        tx[r][c4 + 0] = v.x; tx[r][c4 + 1] = v.y;
        tx[r][c4 + 2] = v.z; tx[r][c4 + 3] = v.w;
    }
    __syncthreads();
#pragma unroll
    for (int l = 0; l < 2; ++l) {
        const int idx = t + l * 256;   // 512 chunks of 8 bf16
        const int c = idx >> 3;
        const int n8 = (idx & 7) * 8;
        unsigned hw[4], lw[4];
#pragma unroll
        for (int jp = 0; jp < 4; ++jp) {
            float v0 = tx[n8 + 2 * jp][c];
            float v1 = tx[n8 + 2 * jp + 1][c];
            u16 h0 = f2bf(v0), h1 = f2bf(v1);
            u16 l0 = f2bf(v0 - bf2f(h0)), l1 = f2bf(v1 - bf2f(h1));
            hw[jp] = (unsigned)h0 | ((unsigned)h1 << 16);
            lw[jp] = (unsigned)l0 | ((unsigned)l1 << 16);
        }
        const size_t off = (size_t)(b * 64 + c) * NN + n0 + n8;
        *(uint4*)(Xth + off) = make_uint4(hw[0], hw[1], hw[2], hw[3]);
        *(uint4*)(Xtl + off) = make_uint4(lw[0], lw[1], lw[2], lw[3]);
    }
}

// ---------------------------------------------------------------------------
// Kernel 3: split-bf16 MFMA GEMM.  C[m][n] = sum_k A[m][k] * Bt[n][k]
//   Tile 128x64 (M x N), BK=32, 4 waves (2Mx2N, 64x32/wave), dbuf LDS 48KB
//   -> 512 blocks = 2 blocks/CU (block-level overlap hides staging drain).
//   XCD-chunked swizzle: lin%8 -> 64-id chunk = 2 B-panels x 32 A-panels.
// ---------------------------------------------------------------------------
#define GLOAD16(g, l) __builtin_amdgcn_global_load_lds( \
    (const __attribute__((address_space(1))) unsigned int*)(g), \
    (__attribute__((address_space(3))) unsigned int*)(l), 16, 0, 0)

template<int EPI>
__global__ __launch_bounds__(256) void gemm_split(
    const u16* __restrict__ Ah, const u16* __restrict__ Al,
    const u16* __restrict__ Bh, const u16* __restrict__ Bl,
    float* __restrict__ Cf, u16* __restrict__ Cth, u16* __restrict__ Ctl)
{
    // LDS chunks of 16B: [buf][ Ah:0..511 | Al:512..1023 | Bh:1024..1279 | Bl:1280..1535 ]
    __shared__ uint4 lds[2][1536];   // 48 KB
    const int t = threadIdx.x;

    // bijective XCD-chunk swizzle (512 % 8 == 0)
    const int lin = blockIdx.x;
    const int swz = ((lin & 7) << 6) | (lin >> 3);
    const int row0 = (swz & 31) * 128;   // M-block
    const int col0 = (swz >> 5) * 64;    // N-block

    // staging geometry: chunk j -> row=j>>2, slot=j&3; source slot inverse-swizzled
    const int j0 = t, j1 = t + 256;            // A arrays: 512 chunks each
    const int r0 = j0 >> 2, r1 = j1 >> 2;
    const int s0 = (j0 & 3) ^ ((j0 >> 3) & 3);
    const int s1 = (j1 & 3) ^ ((j1 >> 3) & 3);
    const size_t aoff0 = (size_t)(row0 + r0) * NN + 8 * s0;
    const size_t aoff1 = (size_t)(row0 + r1) * NN + 8 * s1;
    const size_t boff0 = (size_t)(col0 + r0) * NN + 8 * s0;  // B: 256 chunks (rows 0..63)

    const int lane = t & 63, g = lane >> 4, lr = lane & 15;
    const int wm = t >> 7, wn = (t >> 6) & 1;
    int ia[4], ib[2];
#pragma unroll
    for (int i = 0; i < 4; ++i) {
        const int ra = wm * 64 + 16 * i + lr;
        ia[i] = ra * 4 + (g ^ ((ra >> 1) & 3));
    }
#pragma unroll
    for (int p = 0; p < 2; ++p) {
        const int rb = wn * 32 + 16 * p + lr;
        ib[p] = rb * 4 + (g ^ ((rb >> 1) & 3));
    }

    f32x4 acc[4][2];
    const f32x4 zz = {0.f, 0.f, 0.f, 0.f};
#pragma unroll
    for (int i = 0; i < 4; ++i)
#pragma unroll
        for (int p = 0; p < 2; ++p) acc[i][p] = zz;

#define STAGE(bf, kt) do { \
        GLOAD16(Ah + aoff0 + (kt), &lds[bf][j0]); \
        GLOAD16(Ah + aoff1 + (kt), &lds[bf][j1]); \
        GLOAD16(Al + aoff0 + (kt), &lds[bf][512 + j0]); \
        GLOAD16(Al + aoff1 + (kt), &lds[bf][512 + j1]); \
        GLOAD16(Bh + boff0 + (kt), &lds[bf][1024 + j0]); \
        GLOAD16(Bl + boff0 + (kt), &lds[bf][1280 + j0]); \
    } while (0)

    STAGE(0, 0);
    __syncthreads();

#pragma unroll 2
    for (int kt = 0; kt < NN; kt += 32) {
        const int cur = (kt >> 5) & 1;
        if (kt + 32 < NN) STAGE(cur ^ 1, kt + 32);

        bf16x8 ah[4], al[4], bh[2], bl[2];
#pragma unroll
        for (int i = 0; i < 4; ++i) {
            ah[i] = *(const bf16x8*)&lds[cur][ia[i]];
            al[i] = *(const bf16x8*)&lds[cur][512 + ia[i]];
        }
#pragma unroll
        for (int p = 0; p < 2; ++p) {
            bh[p] = *(const bf16x8*)&lds[cur][1024 + ib[p]];
            bl[p] = *(const bf16x8*)&lds[cur][1280 + ib[p]];
        }
#pragma unroll
        for (int i = 0; i < 4; ++i)
#pragma unroll
            for (int p = 0; p < 2; ++p) {
                acc[i][p] = __builtin_amdgcn_mfma_f32_16x16x32_bf16(ah[i], bh[p], acc[i][p], 0, 0, 0);
                acc[i][p] = __builtin_amdgcn_mfma_f32_16x16x32_bf16(ah[i], bl[p], acc[i][p], 0, 0, 0);
                acc[i][p] = __builtin_amdgcn_mfma_f32_16x16x32_bf16(al[i], bh[p], acc[i][p], 0, 0, 0);
            }
        __syncthreads();
    }

    // epilogue: C/D layout col=lane&15, row=(lane>>4)*4+q  [m89 verified]
#pragma unroll
    for (int i = 0; i < 4; ++i)
#pragma unroll
        for (int p = 0; p < 2; ++p) {
            const int mb = row0 + wm * 64 + 16 * i + g * 4;
            const int c  = col0 + wn * 32 + 16 * p + lr;
#pragma unroll
            for (int q = 0; q < 4; ++q)
                Cf[(size_t)(mb + q) * BC + c] = acc[i][p][q];
            if (EPI == 0) {
                u16 h[4], lo[4];
#pragma unroll
                for (int q = 0; q < 4; ++q) {
                    const float v = acc[i][p][q];
                    h[q]  = f2bf(v);
                    lo[q] = f2bf(v - bf2f(h[q]));
                }
                const size_t toff = (size_t)c * NN + mb;
                *(uint2*)(Cth + toff) =
                    make_uint2((unsigned)h[0] | ((unsigned)h[1] << 16),
                               (unsigned)h[2] | ((unsigned)h[3] << 16));
                *(uint2*)(Ctl + toff) =
                    make_uint2((unsigned)lo[0] | ((unsigned)lo[1] << 16),
                               (unsigned)lo[2] | ((unsigned)lo[3] << 16));
            }
        }
#undef STAGE
}

// ---------------------------------------------------------------------------
// Kernel 4: per-node W build + apply + bias. TWO nodes per block: stream the
// 768KB weights pool ONCE, accumulate node0's W into LDS and node1's W into
// registers (static indexing), then apply sequentially. Halves wp L2 traffic.
// ---------------------------------------------------------------------------
__global__ __launch_bounds__(256) void final_apply(const float* __restrict__ X,
                                                   const float* __restrict__ E,
                                                   const float* __restrict__ G1,
                                                   const float* __restrict__ G2,
                                                   const float* __restrict__ wp,
                                                   const float* __restrict__ bp,
                                                   float* __restrict__ out) {
    const int n0 = blockIdx.x;          // grid 2048
    const int n1 = n0 + 2048;
    const int t = threadIdx.x;
    __shared__ float W[3 * CC * OO];    // 48KB
    __shared__ float xg[3][BC];         // 12KB
    __shared__ float esh0[DD], esh1[DD];
    if (t < DD) { esh0[t] = E[n0 * DD + t]; esh1[t] = E[n1 * DD + t]; }

    // stage xg for node0
#pragma unroll
    for (int l = 0; l < 4; ++l) {
        const int idx = t + l * 256;
        const int b = idx >> 6;
        const int i = idx & 63;
        const float xs = X[(size_t)b * (NN * CC) + (size_t)n0 * CC + i];
        const float g1 = G1[(size_t)n0 * BC + idx];
        const float g2 = G2[(size_t)n0 * BC + idx];
        xg[0][idx] = xs;
        xg[1][idx] = g1;
        xg[2][idx] = 2.0f * g2 - xs;
    }
    __syncthreads();
    float er0[DD], er1[DD];
#pragma unroll
    for (int d = 0; d < DD; ++d) { er0[d] = esh0[d]; er1[d] = esh1[d]; }

    // W generation for BOTH nodes in one wp pass (3072 float4 per d-slice)
    float4 w1[12];
    const float4* wp4 = (const float4*)wp;
#pragma unroll
    for (int l = 0; l < 12; ++l) {
        const int w4 = t + l * 256;
        float4 a0 = make_float4(0.f, 0.f, 0.f, 0.f);
        float4 a1 = make_float4(0.f, 0.f, 0.f, 0.f);
#pragma unroll
        for (int d = 0; d < DD; ++d) {
            float4 v = wp4[d * 3072 + w4];
            a0.x += er0[d] * v.x; a0.y += er0[d] * v.y;
            a0.z += er0[d] * v.z; a0.w += er0[d] * v.w;
            a1.x += er1[d] * v.x; a1.y += er1[d] * v.y;
            a1.z += er1[d] * v.z; a1.w += er1[d] * v.w;
        }
        *(float4*)&W[w4 * 4] = a0;
        w1[l] = a1;
    }
    __syncthreads();

    // apply node0
#pragma unroll
    for (int p = 0; p < 4; ++p) {
        const int idx2 = t + p * 256;
        const int b = idx2 >> 6;
        const int o = idx2 & 63;
        float acc = 0.0f;
#pragma unroll
        for (int d = 0; d < DD; ++d) acc += er0[d] * bp[d * OO + o];
#pragma unroll
        for (int k = 0; k < 3; ++k) {
            const float* wk = &W[k * (CC * OO) + o];
            const float* xk = &xg[k][b * CC];
#pragma unroll 16
            for (int i = 0; i < CC; ++i) acc += xk[i] * wk[i * OO];
        }
        out[(size_t)b * (NN * OO) + (size_t)n0 * OO + o] = acc;
    }
    __syncthreads();   // W/xg still in use above; safe to overwrite after this

    // dump node1's W from registers; restage xg for node1
#pragma unroll
    for (int l = 0; l < 12; ++l) *(float4*)&W[(t + l * 256) * 4] = w1[l];
#pragma unroll
    for (int l = 0; l < 4; ++l) {
        const int idx = t + l * 256;
        const int b = idx >> 6;
        const int i = idx & 63;
        const float xs = X[(size_t)b * (NN * CC) + (size_t)n1 * CC + i];
        const float g1 = G1[(size_t)n1 * BC + idx];
        const float g2 = G2[(size_t)n1 * BC + idx];
        xg[0][idx] = xs;
        xg[1][idx] = g1;
        xg[2][idx] = 2.0f * g2 - xs;
    }
    __syncthreads();

    // apply node1
#pragma unroll
    for (int p = 0; p < 4; ++p) {
        const int idx2 = t + p * 256;
        const int b = idx2 >> 6;
        const int o = idx2 & 63;
        float acc = 0.0f;
#pragma unroll
        for (int d = 0; d < DD; ++d) acc += er1[d] * bp[d * OO + o];
#pragma unroll
        for (int k = 0; k < 3; ++k) {
            const float* wk = &W[k * (CC * OO) + o];
            const float* xk = &xg[k][b * CC];
#pragma unroll 16
            for (int i = 0; i < CC; ++i) acc += xk[i] * wk[i * OO];
        }
        out[(size_t)b * (NN * OO) + (size_t)n1 * OO + o] = acc;
    }
}

// ---------------------------------------------------------------------------
extern "C" void kernel_launch(void* const* d_in, const int* in_sizes, int n_in,
                              void* d_out, int out_size, void* d_ws, size_t ws_size,
                              hipStream_t stream) {
    const float* X  = (const float*)d_in[0];   // [16,4096,64]
    const float* E  = (const float*)d_in[1];   // [4096,16]
    const float* wp = (const float*)d_in[3];   // [16,3,64,64]
    const float* bp = (const float*)d_in[4];   // [16,64]
    float* out = (float*)d_out;                // [16,4096,64]

    // ws layout (112 MB):
    u16* Ah   = (u16*)d_ws;                        // 32 MB
    u16* Al   = Ah   + (size_t)NN * NN;            // 32 MB
    u16* Xth  = Al   + (size_t)NN * NN;            //  8 MB
    u16* Xtl  = Xth  + (size_t)BC * NN;            //  8 MB
    u16* G1th = Xtl  + (size_t)BC * NN;            //  8 MB
    u16* G1tl = G1th + (size_t)BC * NN;            //  8 MB
    float* G1f = (float*)(G1tl + (size_t)BC * NN); // 16 MB
    float* G2f = (float*)Xth;                      // overlay: Xt dead after GEMM1

    softmax_adj<<<NN, 256, 0, stream>>>(E, Ah, Al);
    pack_xt<<<dim3(NN / 64, BB), 256, 0, stream>>>(X, Xth, Xtl);
    gemm_split<0><<<512, 256, 0, stream>>>(Ah, Al, Xth, Xtl, G1f, G1th, G1tl);
    gemm_split<1><<<512, 256, 0, stream>>>(Ah, Al, G1th, G1tl, G2f, nullptr, nullptr);
    final_apply<<<2048, 256, 0, stream>>>(X, E, G1f, G2f, wp, bp, out);
}

// Round 9
// 522.439 us; speedup vs baseline: 1.8943x; 1.8943x over previous
//
#include <hip/hip_runtime.h>

// Problem constants (B=16, N=4096, C=64, O=64, D=16, K=3)
#define NN 4096
#define DD 16
#define BB 16
#define CC 64
#define OO 64
#define BC 1024   // BB*CC

typedef unsigned short u16;
typedef __attribute__((ext_vector_type(8))) short bf16x8;
typedef __attribute__((ext_vector_type(4))) float f32x4;

__device__ __forceinline__ u16 f2bf(float f) {
    unsigned u = __builtin_bit_cast(unsigned, f);
    unsigned r = u + 0x7FFFu + ((u >> 16) & 1u);
    return (u16)(r >> 16);
}
__device__ __forceinline__ float bf2f(u16 h) {
    unsigned u = ((unsigned)h) << 16;
    return __builtin_bit_cast(float, u);
}

// ---------------------------------------------------------------------------
// Kernel 1: A = softmax(relu(E @ E^T), axis=1) -> split bf16 (Ah + Al)
// ---------------------------------------------------------------------------
__global__ __launch_bounds__(256) void softmax_adj(const float* __restrict__ E,
                                                   u16* __restrict__ Ah,
                                                   u16* __restrict__ Al) {
    const int i = blockIdx.x;
    const int t = threadIdx.x;
    __shared__ float esh[DD];
    __shared__ float redm[4], reds[4];
    if (t < DD) esh[t] = E[i * DD + t];
    __syncthreads();
    float er[DD];
#pragma unroll
    for (int d = 0; d < DD; ++d) er[d] = esh[d];

    float v[16];
    float m = 0.0f;  // relu => max >= 0
#pragma unroll
    for (int s = 0; s < 16; ++s) {
        const int j = s * 256 + t;
        const float4* ej = (const float4*)(E + j * DD);
        float4 a0 = ej[0], a1 = ej[1], a2 = ej[2], a3 = ej[3];
        float dot = a0.x * er[0] + a0.y * er[1] + a0.z * er[2] + a0.w * er[3]
                  + a1.x * er[4] + a1.y * er[5] + a1.z * er[6] + a1.w * er[7]
                  + a2.x * er[8] + a2.y * er[9] + a2.z * er[10] + a2.w * er[11]
                  + a3.x * er[12] + a3.y * er[13] + a3.z * er[14] + a3.w * er[15];
        v[s] = fmaxf(dot, 0.0f);
        m = fmaxf(m, v[s]);
    }
#pragma unroll
    for (int off = 1; off < 64; off <<= 1) m = fmaxf(m, __shfl_xor(m, off));
    const int wave = t >> 6, lane = t & 63;
    if (lane == 0) redm[wave] = m;
    __syncthreads();
    m = fmaxf(fmaxf(redm[0], redm[1]), fmaxf(redm[2], redm[3]));

    float sum = 0.0f;
#pragma unroll
    for (int s = 0; s < 16; ++s) {
        v[s] = expf(v[s] - m);
        sum += v[s];
    }
#pragma unroll
    for (int off = 1; off < 64; off <<= 1) sum += __shfl_xor(sum, off);
    if (lane == 0) reds[wave] = sum;
    __syncthreads();
    const float rinv = 1.0f / (reds[0] + reds[1] + reds[2] + reds[3]);
#pragma unroll
    for (int s = 0; s < 16; ++s) {
        const float val = v[s] * rinv;
        const u16 hh = f2bf(val);
        Ah[(size_t)i * NN + s * 256 + t] = hh;
        Al[(size_t)i * NN + s * 256 + t] = f2bf(val - bf2f(hh));
    }
}

// ---------------------------------------------------------------------------
// Kernel 2: transpose+split X [B,N,C] -> Xt_{h,l} [BC=b*64+c][N] bf16
// ---------------------------------------------------------------------------
__global__ __launch_bounds__(256) void pack_xt(const float* __restrict__ X,
                                               u16* __restrict__ Xth,
                                               u16* __restrict__ Xtl) {
    const int n0 = blockIdx.x * 64;
    const int b  = blockIdx.y;
    const int t  = threadIdx.x;
    __shared__ float tx[64][68];
    const float* src = X + (size_t)b * (NN * CC) + (size_t)n0 * CC;
#pragma unroll
    for (int l = 0; l < 4; ++l) {
        const int idx = t + l * 256;   // 1024 float4 chunks
        const int r = idx >> 4;
        const int c4 = (idx & 15) * 4;
        float4 v = *(const float4*)(src + r * CC + c4);
        tx[r][c4 + 0] = v.x; tx[r][c4 + 1] = v.y;
        tx[r][c4 + 2] = v.z; tx[r][c4 + 3] = v.w;
    }
    __syncthreads();
#pragma unroll
    for (int l = 0; l < 2; ++l) {
        const int idx = t + l * 256;   // 512 chunks of 8 bf16
        const int c = idx >> 3;
        const int n8 = (idx & 7) * 8;
        unsigned hw[4], lw[4];
#pragma unroll
        for (int jp = 0; jp < 4; ++jp) {
            float v0 = tx[n8 + 2 * jp][c];
            float v1 = tx[n8 + 2 * jp + 1][c];
            u16 h0 = f2bf(v0), h1 = f2bf(v1);
            u16 l0 = f2bf(v0 - bf2f(h0)), l1 = f2bf(v1 - bf2f(h1));
            hw[jp] = (unsigned)h0 | ((unsigned)h1 << 16);
            lw[jp] = (unsigned)l0 | ((unsigned)l1 << 16);
        }
        const size_t off = (size_t)(b * 64 + c) * NN + n0 + n8;
        *(uint4*)(Xth + off) = make_uint4(hw[0], hw[1], hw[2], hw[3]);
        *(uint4*)(Xtl + off) = make_uint4(lw[0], lw[1], lw[2], lw[3]);
    }
}

// ---------------------------------------------------------------------------
// Kernel 3: split-bf16 MFMA GEMM, 2-way K-SPLIT.
//   C[m][n] = sum_k A[m][k]*Bt[n][k]; tile 128x128, BK=32, 4 waves, dbuf 64KB.
//   grid 512 = 256 tiles x 2 K-halves -> 2 blocks/CU (8 waves/CU concurrency)
//   at rd3's low staged traffic (1.02 GB). Writes f32 partials P0/P1.
//   XCD mapping: col panel = lin%8 (same B panel per XCD).
// ---------------------------------------------------------------------------
#define GLOAD16(g, l) __builtin_amdgcn_global_load_lds( \
    (const __attribute__((address_space(1))) unsigned int*)(g), \
    (__attribute__((address_space(3))) unsigned int*)(l), 16, 0, 0)

__global__ __launch_bounds__(256) void gemm_ks(
    const u16* __restrict__ Ah, const u16* __restrict__ Al,
    const u16* __restrict__ Bh, const u16* __restrict__ Bl,
    float* __restrict__ P0, float* __restrict__ P1)
{
    __shared__ uint4 lds[2][4][512];   // [buf][Ah,Al,Bh,Bl][128 rows x 4 slots]
    const int t = threadIdx.x;

    const int lin = blockIdx.x;
    const int col0  = (lin & 7) * 128;          // col panel = XCD id (rr dispatch)
    const int row0  = ((lin >> 3) & 31) * 128;
    const int khalf = lin >> 8;                 // 0 / 1
    const int kbase = khalf * 2048;
    float* __restrict__ Pf = khalf ? P1 : P0;

    // staging geometry: chunk j -> row=j>>2, slot=j&3; source slot inverse-swizzled
    const int j0 = t, j1 = t + 256;
    const int r0 = j0 >> 2, r1 = j1 >> 2;
    const int s0 = (j0 & 3) ^ ((j0 >> 3) & 3);
    const int s1 = (j1 & 3) ^ ((j1 >> 3) & 3);
    const size_t aoff0 = (size_t)(row0 + r0) * NN + 8 * s0 + kbase;
    const size_t aoff1 = (size_t)(row0 + r1) * NN + 8 * s1 + kbase;
    const size_t boff0 = (size_t)(col0 + r0) * NN + 8 * s0 + kbase;
    const size_t boff1 = (size_t)(col0 + r1) * NN + 8 * s1 + kbase;

    const int lane = t & 63, g = lane >> 4, lr = lane & 15;
    const int wm = t >> 7, wn = (t >> 6) & 1;
    int ia[4], ib[4];
#pragma unroll
    for (int i = 0; i < 4; ++i) {
        const int ra = wm * 64 + 16 * i + lr;
        ia[i] = ra * 4 + (g ^ ((ra >> 1) & 3));
        const int rb = wn * 64 + 16 * i + lr;
        ib[i] = rb * 4 + (g ^ ((rb >> 1) & 3));
    }

    f32x4 acc[4][4];
    const f32x4 zz = {0.f, 0.f, 0.f, 0.f};
#pragma unroll
    for (int i = 0; i < 4; ++i)
#pragma unroll
        for (int p = 0; p < 4; ++p) acc[i][p] = zz;

#define STAGE(bf, kt) do { \
        GLOAD16(Ah + aoff0 + (kt), &lds[bf][0][j0]); \
        GLOAD16(Ah + aoff1 + (kt), &lds[bf][0][j1]); \
        GLOAD16(Al + aoff0 + (kt), &lds[bf][1][j0]); \
        GLOAD16(Al + aoff1 + (kt), &lds[bf][1][j1]); \
        GLOAD16(Bh + boff0 + (kt), &lds[bf][2][j0]); \
        GLOAD16(Bh + boff1 + (kt), &lds[bf][2][j1]); \
        GLOAD16(Bl + boff0 + (kt), &lds[bf][3][j0]); \
        GLOAD16(Bl + boff1 + (kt), &lds[bf][3][j1]); \
    } while (0)

    STAGE(0, 0);
    __syncthreads();

#pragma unroll 2
    for (int kt = 0; kt < 2048; kt += 32) {
        const int cur = (kt >> 5) & 1;
        if (kt + 32 < 2048) STAGE(cur ^ 1, kt + 32);

        bf16x8 ah[4], al[4], bh[4], bl[4];
#pragma unroll
        for (int i = 0; i < 4; ++i) {
            ah[i] = *(const bf16x8*)&lds[cur][0][ia[i]];
            al[i] = *(const bf16x8*)&lds[cur][1][ia[i]];
            bh[i] = *(const bf16x8*)&lds[cur][2][ib[i]];
            bl[i] = *(const bf16x8*)&lds[cur][3][ib[i]];
        }
#pragma unroll
        for (int i = 0; i < 4; ++i)
#pragma unroll
            for (int p = 0; p < 4; ++p) {
                acc[i][p] = __builtin_amdgcn_mfma_f32_16x16x32_bf16(ah[i], bh[p], acc[i][p], 0, 0, 0);
                acc[i][p] = __builtin_amdgcn_mfma_f32_16x16x32_bf16(ah[i], bl[p], acc[i][p], 0, 0, 0);
                acc[i][p] = __builtin_amdgcn_mfma_f32_16x16x32_bf16(al[i], bh[p], acc[i][p], 0, 0, 0);
            }
        __syncthreads();
    }

    // epilogue: f32 partial only. C/D layout col=lane&15, row=(lane>>4)*4+q.
#pragma unroll
    for (int i = 0; i < 4; ++i)
#pragma unroll
        for (int p = 0; p < 4; ++p) {
            const int mb = row0 + wm * 64 + 16 * i + g * 4;
            const int c  = col0 + wn * 64 + 16 * p + lr;
#pragma unroll
            for (int q = 0; q < 4; ++q)
                Pf[(size_t)(mb + q) * BC + c] = acc[i][p][q];
        }
#undef STAGE
}

// ---------------------------------------------------------------------------
// Kernel 3b: reduce partials + transpose-split epilogue for G1.
//   G1f = P0 + P1 (in-place into P0 region); G1t_{h,l}[c][n] = split(G1f^T).
//   grid (NN/64, BC/64). Same transpose pattern as pack_xt (verified).
// ---------------------------------------------------------------------------
__global__ __launch_bounds__(256) void reduce_t(float* __restrict__ P0,
                                                const float* __restrict__ P1,
                                                u16* __restrict__ G1th,
                                                u16* __restrict__ G1tl) {
    const int n0 = blockIdx.x * 64;
    const int c0 = blockIdx.y * 64;
    const int t  = threadIdx.x;
    __shared__ float tx[64][68];
#pragma unroll
    for (int l = 0; l < 4; ++l) {
        const int idx = t + l * 256;   // 1024 float4 chunks of the 64x64 tile
        const int r = idx >> 4;
        const int c4 = (idx & 15) * 4;
        const size_t off = (size_t)(n0 + r) * BC + c0 + c4;
        float4 v0 = *(const float4*)(P0 + off);
        float4 v1 = *(const float4*)(P1 + off);
        float4 s = make_float4(v0.x + v1.x, v0.y + v1.y, v0.z + v1.z, v0.w + v1.w);
        *(float4*)(P0 + off) = s;   // G1f in-place (block owns its tile)
        tx[r][c4 + 0] = s.x; tx[r][c4 + 1] = s.y;
        tx[r][c4 + 2] = s.z; tx[r][c4 + 3] = s.w;
    }
    __syncthreads();
#pragma unroll
    for (int l = 0; l < 2; ++l) {
        const int idx = t + l * 256;   // 512 chunks of 8 bf16
        const int c = idx >> 3;
        const int n8 = (idx & 7) * 8;
        unsigned hw[4], lw[4];
#pragma unroll
        for (int jp = 0; jp < 4; ++jp) {
            float v0 = tx[n8 + 2 * jp][c];
            float v1 = tx[n8 + 2 * jp + 1][c];
            u16 h0 = f2bf(v0), h1 = f2bf(v1);
            u16 l0 = f2bf(v0 - bf2f(h0)), l1 = f2bf(v1 - bf2f(h1));
            hw[jp] = (unsigned)h0 | ((unsigned)h1 << 16);
            lw[jp] = (unsigned)l0 | ((unsigned)l1 << 16);
        }
        const size_t off = (size_t)(c0 + c) * NN + n0 + n8;
        *(uint4*)(G1th + off) = make_uint4(hw[0], hw[1], hw[2], hw[3]);
        *(uint4*)(G1tl + off) = make_uint4(lw[0], lw[1], lw[2], lw[3]);
    }
}

// ---------------------------------------------------------------------------
// Kernel 3c: linear partial reduce for G2: G2f += P1 (in-place).
// ---------------------------------------------------------------------------
__global__ __launch_bounds__(256) void reduce_lin(float* __restrict__ G2f,
                                                  const float* __restrict__ P1) {
    const int idx = blockIdx.x * 256 + threadIdx.x;   // over NN*BC/4 float4s
    float4 a = ((const float4*)G2f)[idx];
    float4 b = ((const float4*)P1)[idx];
    ((float4*)G2f)[idx] = make_float4(a.x + b.x, a.y + b.y, a.z + b.z, a.w + b.w);
}

// ---------------------------------------------------------------------------
// Kernel 4: per-node W build + apply + bias (rd3 1-node version — the 2-node
// register variant spilled: VGPR 256, 698MB scratch writes, 563us. Reverted.)
// ---------------------------------------------------------------------------
__global__ __launch_bounds__(256) void final_apply(const float* __restrict__ X,
                                                   const float* __restrict__ E,
                                                   const float* __restrict__ G1,
                                                   const float* __restrict__ G2,
                                                   const float* __restrict__ wp,
                                                   const float* __restrict__ bp,
                                                   float* __restrict__ out) {
    const int n = blockIdx.x;
    const int t = threadIdx.x;
    __shared__ float W[3 * CC * OO];   // 48KB
    __shared__ float xg[3][BC];        // 12KB
    __shared__ float esh[DD];
    if (t < DD) esh[t] = E[n * DD + t];
#pragma unroll
    for (int l = 0; l < 4; ++l) {
        const int idx = t + l * 256;
        const int b = idx >> 6;
        const int i = idx & 63;
        const float xs = X[(size_t)b * (NN * CC) + (size_t)n * CC + i];
        const float g1 = G1[(size_t)n * BC + idx];
        const float g2 = G2[(size_t)n * BC + idx];
        xg[0][idx] = xs;
        xg[1][idx] = g1;
        xg[2][idx] = 2.0f * g2 - xs;
    }
    __syncthreads();
    float er[DD];
#pragma unroll
    for (int d = 0; d < DD; ++d) er[d] = esh[d];

    const float4* wp4 = (const float4*)wp;
#pragma unroll
    for (int l = 0; l < 12; ++l) {
        const int w4 = t + l * 256;
        float4 a = make_float4(0.f, 0.f, 0.f, 0.f);
#pragma unroll
        for (int d = 0; d < DD; ++d) {
            float4 v = wp4[d * 3072 + w4];
            a.x += er[d] * v.x;
            a.y += er[d] * v.y;
            a.z += er[d] * v.z;
            a.w += er[d] * v.w;
        }
        *(float4*)&W[w4 * 4] = a;
    }
    __syncthreads();

#pragma unroll
    for (int p = 0; p < 4; ++p) {
        const int idx2 = t + p * 256;
        const int b = idx2 >> 6;
        const int o = idx2 & 63;
        float acc = 0.0f;
#pragma unroll
        for (int d = 0; d < DD; ++d) acc += er[d] * bp[d * OO + o];
#pragma unroll
        for (int k = 0; k < 3; ++k) {
            const float* wk = &W[k * (CC * OO) + o];
            const float* xk = &xg[k][b * CC];
#pragma unroll 16
            for (int i = 0; i < CC; ++i) acc += xk[i] * wk[i * OO];
        }
        out[(size_t)b * (NN * OO) + (size_t)n * OO + o] = acc;
    }
}

// ---------------------------------------------------------------------------
extern "C" void kernel_launch(void* const* d_in, const int* in_sizes, int n_in,
                              void* d_out, int out_size, void* d_ws, size_t ws_size,
                              hipStream_t stream) {
    const float* X  = (const float*)d_in[0];   // [16,4096,64]
    const float* E  = (const float*)d_in[1];   // [4096,16]
    const float* wp = (const float*)d_in[3];   // [16,3,64,64]
    const float* bp = (const float*)d_in[4];   // [16,64]
    float* out = (float*)d_out;                // [16,4096,64]

    // ws layout (128 MB):
    u16* Ah   = (u16*)d_ws;                        // 32 MB
    u16* Al   = Ah   + (size_t)NN * NN;            // 32 MB
    u16* Xth  = Al   + (size_t)NN * NN;            //  8 MB
    u16* Xtl  = Xth  + (size_t)BC * NN;            //  8 MB
    u16* G1th = Xtl  + (size_t)BC * NN;            //  8 MB
    u16* G1tl = G1th + (size_t)BC * NN;            //  8 MB
    float* G1f = (float*)(G1tl + (size_t)BC * NN); // 16 MB (= gemm1 P0 slot)
    float* P1  = G1f + (size_t)NN * BC;            // 16 MB (shared partial slot)
    float* G2f = (float*)Xth;                      // overlay: Xt dead after gemm1
                                                   //   (= gemm2 P0 slot, 16 MB)

    softmax_adj<<<NN, 256, 0, stream>>>(E, Ah, Al);
    pack_xt<<<dim3(NN / 64, BB), 256, 0, stream>>>(X, Xth, Xtl);
    // GEMM1: G1 = A @ Xt^T  (K-split partials, then reduce + transpose-split)
    gemm_ks<<<512, 256, 0, stream>>>(Ah, Al, Xth, Xtl, G1f, P1);
    reduce_t<<<dim3(NN / 64, BC / 64), 256, 0, stream>>>(G1f, P1, G1th, G1tl);
    // GEMM2: G2 = A @ G1t^T
    gemm_ks<<<512, 256, 0, stream>>>(Ah, Al, G1th, G1tl, G2f, P1);
    reduce_lin<<<(NN * BC / 4) / 256, 256, 0, stream>>>(G2f, P1);
    final_apply<<<NN, 256, 0, stream>>>(X, E, G1f, G2f, wp, bp, out);
}

// Round 10
// 493.889 us; speedup vs baseline: 2.0038x; 1.0578x over previous
//
#include <hip/hip_runtime.h>

// Problem constants (B=16, N=4096, C=64, O=64, D=16, K=3)
#define NN 4096
#define DD 16
#define BB 16
#define CC 64
#define OO 64
#define BC 1024   // BB*CC

typedef unsigned short u16;
typedef unsigned int u32;
typedef __attribute__((ext_vector_type(8))) short bf16x8;
typedef __attribute__((ext_vector_type(4))) float f32x4;

__device__ __forceinline__ u16 f2bf(float f) {
    unsigned u = __builtin_bit_cast(unsigned, f);
    unsigned r = u + 0x7FFFu + ((u >> 16) & 1u);
    return (u16)(r >> 16);
}
__device__ __forceinline__ float bf2f(u16 h) {
    unsigned u = ((unsigned)h) << 16;
    return __builtin_bit_cast(float, u);
}

// ---------------------------------------------------------------------------
// Kernel 1: A = softmax(relu(E @ E^T), axis=1) -> split bf16 (Ah + Al)
// ---------------------------------------------------------------------------
__global__ __launch_bounds__(256) void softmax_adj(const float* __restrict__ E,
                                                   u16* __restrict__ Ah,
                                                   u16* __restrict__ Al) {
    const int i = blockIdx.x;
    const int t = threadIdx.x;
    __shared__ float esh[DD];
    __shared__ float redm[4], reds[4];
    if (t < DD) esh[t] = E[i * DD + t];
    __syncthreads();
    float er[DD];
#pragma unroll
    for (int d = 0; d < DD; ++d) er[d] = esh[d];

    float v[16];
    float m = 0.0f;  // relu => max >= 0
#pragma unroll
    for (int s = 0; s < 16; ++s) {
        const int j = s * 256 + t;
        const float4* ej = (const float4*)(E + j * DD);
        float4 a0 = ej[0], a1 = ej[1], a2 = ej[2], a3 = ej[3];
        float dot = a0.x * er[0] + a0.y * er[1] + a0.z * er[2] + a0.w * er[3]
                  + a1.x * er[4] + a1.y * er[5] + a1.z * er[6] + a1.w * er[7]
                  + a2.x * er[8] + a2.y * er[9] + a2.z * er[10] + a2.w * er[11]
                  + a3.x * er[12] + a3.y * er[13] + a3.z * er[14] + a3.w * er[15];
        v[s] = fmaxf(dot, 0.0f);
        m = fmaxf(m, v[s]);
    }
#pragma unroll
    for (int off = 1; off < 64; off <<= 1) m = fmaxf(m, __shfl_xor(m, off));
    const int wave = t >> 6, lane = t & 63;
    if (lane == 0) redm[wave] = m;
    __syncthreads();
    m = fmaxf(fmaxf(redm[0], redm[1]), fmaxf(redm[2], redm[3]));

    float sum = 0.0f;
#pragma unroll
    for (int s = 0; s < 16; ++s) {
        v[s] = expf(v[s] - m);
        sum += v[s];
    }
#pragma unroll
    for (int off = 1; off < 64; off <<= 1) sum += __shfl_xor(sum, off);
    if (lane == 0) reds[wave] = sum;
    __syncthreads();
    const float rinv = 1.0f / (reds[0] + reds[1] + reds[2] + reds[3]);
#pragma unroll
    for (int s = 0; s < 16; ++s) {
        const float val = v[s] * rinv;
        const u16 hh = f2bf(val);
        Ah[(size_t)i * NN + s * 256 + t] = hh;
        Al[(size_t)i * NN + s * 256 + t] = f2bf(val - bf2f(hh));
    }
}

// ---------------------------------------------------------------------------
// Kernel 2: transpose+split X [B,N,C] -> Xt_{h,l} [BC=b*64+c][N] bf16
// ---------------------------------------------------------------------------
__global__ __launch_bounds__(256) void pack_xt(const float* __restrict__ X,
                                               u16* __restrict__ Xth,
                                               u16* __restrict__ Xtl) {
    const int n0 = blockIdx.x * 64;
    const int b  = blockIdx.y;
    const int t  = threadIdx.x;
    __shared__ float tx[64][68];
    const float* src = X + (size_t)b * (NN * CC) + (size_t)n0 * CC;
#pragma unroll
    for (int l = 0; l < 4; ++l) {
        const int idx = t + l * 256;   // 1024 float4 chunks
        const int r = idx >> 4;
        const int c4 = (idx & 15) * 4;
        float4 v = *(const float4*)(src + r * CC + c4);
        tx[r][c4 + 0] = v.x; tx[r][c4 + 1] = v.y;
        tx[r][c4 + 2] = v.z; tx[r][c4 + 3] = v.w;
    }
    __syncthreads();
#pragma unroll
    for (int l = 0; l < 2; ++l) {
        const int idx = t + l * 256;   // 512 chunks of 8 bf16
        const int c = idx >> 3;
        const int n8 = (idx & 7) * 8;
        unsigned hw[4], lw[4];
#pragma unroll
        for (int jp = 0; jp < 4; ++jp) {
            float v0 = tx[n8 + 2 * jp][c];
            float v1 = tx[n8 + 2 * jp + 1][c];
            u16 h0 = f2bf(v0), h1 = f2bf(v1);
            u16 l0 = f2bf(v0 - bf2f(h0)), l1 = f2bf(v1 - bf2f(h1));
            hw[jp] = (unsigned)h0 | ((unsigned)h1 << 16);
            lw[jp] = (unsigned)l0 | ((unsigned)l1 << 16);
        }
        const size_t off = (size_t)(b * 64 + c) * NN + n0 + n8;
        *(uint4*)(Xth + off) = make_uint4(hw[0], hw[1], hw[2], hw[3]);
        *(uint4*)(Xtl + off) = make_uint4(lw[0], lw[1], lw[2], lw[3]);
    }
}

// ---------------------------------------------------------------------------
// Kernel 3: split-bf16 MFMA GEMM, 2-way K-SPLIT (unchanged from rd9: ~140us).
// ---------------------------------------------------------------------------
#define GLOAD16(g, l) __builtin_amdgcn_global_load_lds( \
    (const __attribute__((address_space(1))) unsigned int*)(g), \
    (__attribute__((address_space(3))) unsigned int*)(l), 16, 0, 0)

__global__ __launch_bounds__(256) void gemm_ks(
    const u16* __restrict__ Ah, const u16* __restrict__ Al,
    const u16* __restrict__ Bh, const u16* __restrict__ Bl,
    float* __restrict__ P0, float* __restrict__ P1)
{
    __shared__ uint4 lds[2][4][512];   // [buf][Ah,Al,Bh,Bl][128 rows x 4 slots]
    const int t = threadIdx.x;

    const int lin = blockIdx.x;
    const int col0  = (lin & 7) * 128;          // col panel = XCD id (rr dispatch)
    const int row0  = ((lin >> 3) & 31) * 128;
    const int khalf = lin >> 8;                 // 0 / 1
    const int kbase = khalf * 2048;
    float* __restrict__ Pf = khalf ? P1 : P0;

    // staging geometry: chunk j -> row=j>>2, slot=j&3; source slot inverse-swizzled
    const int j0 = t, j1 = t + 256;
    const int r0 = j0 >> 2, r1 = j1 >> 2;
    const int s0 = (j0 & 3) ^ ((j0 >> 3) & 3);
    const int s1 = (j1 & 3) ^ ((j1 >> 3) & 3);
    const size_t aoff0 = (size_t)(row0 + r0) * NN + 8 * s0 + kbase;
    const size_t aoff1 = (size_t)(row0 + r1) * NN + 8 * s1 + kbase;
    const size_t boff0 = (size_t)(col0 + r0) * NN + 8 * s0 + kbase;
    const size_t boff1 = (size_t)(col0 + r1) * NN + 8 * s1 + kbase;

    const int lane = t & 63, g = lane >> 4, lr = lane & 15;
    const int wm = t >> 7, wn = (t >> 6) & 1;
    int ia[4], ib[4];
#pragma unroll
    for (int i = 0; i < 4; ++i) {
        const int ra = wm * 64 + 16 * i + lr;
        ia[i] = ra * 4 + (g ^ ((ra >> 1) & 3));
        const int rb = wn * 64 + 16 * i + lr;
        ib[i] = rb * 4 + (g ^ ((rb >> 1) & 3));
    }

    f32x4 acc[4][4];
    const f32x4 zz = {0.f, 0.f, 0.f, 0.f};
#pragma unroll
    for (int i = 0; i < 4; ++i)
#pragma unroll
        for (int p = 0; p < 4; ++p) acc[i][p] = zz;

#define STAGE(bf, kt) do { \
        GLOAD16(Ah + aoff0 + (kt), &lds[bf][0][j0]); \
        GLOAD16(Ah + aoff1 + (kt), &lds[bf][0][j1]); \
        GLOAD16(Al + aoff0 + (kt), &lds[bf][1][j0]); \
        GLOAD16(Al + aoff1 + (kt), &lds[bf][1][j1]); \
        GLOAD16(Bh + boff0 + (kt), &lds[bf][2][j0]); \
        GLOAD16(Bh + boff1 + (kt), &lds[bf][2][j1]); \
        GLOAD16(Bl + boff0 + (kt), &lds[bf][3][j0]); \
        GLOAD16(Bl + boff1 + (kt), &lds[bf][3][j1]); \
    } while (0)

    STAGE(0, 0);
    __syncthreads();

#pragma unroll 2
    for (int kt = 0; kt < 2048; kt += 32) {
        const int cur = (kt >> 5) & 1;
        if (kt + 32 < 2048) STAGE(cur ^ 1, kt + 32);

        bf16x8 ah[4], al[4], bh[4], bl[4];
#pragma unroll
        for (int i = 0; i < 4; ++i) {
            ah[i] = *(const bf16x8*)&lds[cur][0][ia[i]];
            al[i] = *(const bf16x8*)&lds[cur][1][ia[i]];
            bh[i] = *(const bf16x8*)&lds[cur][2][ib[i]];
            bl[i] = *(const bf16x8*)&lds[cur][3][ib[i]];
        }
#pragma unroll
        for (int i = 0; i < 4; ++i)
#pragma unroll
            for (int p = 0; p < 4; ++p) {
                acc[i][p] = __builtin_amdgcn_mfma_f32_16x16x32_bf16(ah[i], bh[p], acc[i][p], 0, 0, 0);
                acc[i][p] = __builtin_amdgcn_mfma_f32_16x16x32_bf16(ah[i], bl[p], acc[i][p], 0, 0, 0);
                acc[i][p] = __builtin_amdgcn_mfma_f32_16x16x32_bf16(al[i], bh[p], acc[i][p], 0, 0, 0);
            }
        __syncthreads();
    }

    // epilogue: f32 partial only. C/D layout col=lane&15, row=(lane>>4)*4+q.
#pragma unroll
    for (int i = 0; i < 4; ++i)
#pragma unroll
        for (int p = 0; p < 4; ++p) {
            const int mb = row0 + wm * 64 + 16 * i + g * 4;
            const int c  = col0 + wn * 64 + 16 * p + lr;
#pragma unroll
            for (int q = 0; q < 4; ++q)
                Pf[(size_t)(mb + q) * BC + c] = acc[i][p][q];
        }
#undef STAGE
}

// ---------------------------------------------------------------------------
// Kernel 3b: reduce partials + transpose-split epilogue for G1. (unchanged)
// ---------------------------------------------------------------------------
__global__ __launch_bounds__(256) void reduce_t(float* __restrict__ P0,
                                                const float* __restrict__ P1,
                                                u16* __restrict__ G1th,
                                                u16* __restrict__ G1tl) {
    const int n0 = blockIdx.x * 64;
    const int c0 = blockIdx.y * 64;
    const int t  = threadIdx.x;
    __shared__ float tx[64][68];
#pragma unroll
    for (int l = 0; l < 4; ++l) {
        const int idx = t + l * 256;   // 1024 float4 chunks of the 64x64 tile
        const int r = idx >> 4;
        const int c4 = (idx & 15) * 4;
        const size_t off = (size_t)(n0 + r) * BC + c0 + c4;
        float4 v0 = *(const float4*)(P0 + off);
        float4 v1 = *(const float4*)(P1 + off);
        float4 s = make_float4(v0.x + v1.x, v0.y + v1.y, v0.z + v1.z, v0.w + v1.w);
        *(float4*)(P0 + off) = s;   // G1f in-place (block owns its tile)
        tx[r][c4 + 0] = s.x; tx[r][c4 + 1] = s.y;
        tx[r][c4 + 2] = s.z; tx[r][c4 + 3] = s.w;
    }
    __syncthreads();
#pragma unroll
    for (int l = 0; l < 2; ++l) {
        const int idx = t + l * 256;   // 512 chunks of 8 bf16
        const int c = idx >> 3;
        const int n8 = (idx & 7) * 8;
        unsigned hw[4], lw[4];
#pragma unroll
        for (int jp = 0; jp < 4; ++jp) {
            float v0 = tx[n8 + 2 * jp][c];
            float v1 = tx[n8 + 2 * jp + 1][c];
            u16 h0 = f2bf(v0), h1 = f2bf(v1);
            u16 l0 = f2bf(v0 - bf2f(h0)), l1 = f2bf(v1 - bf2f(h1));
            hw[jp] = (unsigned)h0 | ((unsigned)h1 << 16);
            lw[jp] = (unsigned)l0 | ((unsigned)l1 << 16);
        }
        const size_t off = (size_t)(c0 + c) * NN + n0 + n8;
        *(uint4*)(G1th + off) = make_uint4(hw[0], hw[1], hw[2], hw[3]);
        *(uint4*)(G1tl + off) = make_uint4(lw[0], lw[1], lw[2], lw[3]);
    }
}

// ---------------------------------------------------------------------------
// Kernel 3c: linear partial reduce for G2: G2f += P1 (in-place). (unchanged)
// ---------------------------------------------------------------------------
__global__ __launch_bounds__(256) void reduce_lin(float* __restrict__ G2f,
                                                  const float* __restrict__ P1) {
    const int idx = blockIdx.x * 256 + threadIdx.x;   // over NN*BC/4 float4s
    float4 a = ((const float4*)G2f)[idx];
    float4 b = ((const float4*)P1)[idx];
    ((float4*)G2f)[idx] = make_float4(a.x + b.x, a.y + b.y, a.z + b.z, a.w + b.w);
}

// ---------------------------------------------------------------------------
// Kernel 4 v3: 4 nodes x 32-o-half per block, 512 threads.
//   Cuts wp L2 traffic 3.2GB -> 805MB (each wp float4 read once, accumulated
//   into 4 per-node W's via STATIC-indexed regs). W f32 in LDS, apply reads
//   it as float4 (8x fewer LDS instrs than rd9's scalar reads). xg in bf16
//   (+<3e-3 err) to fit LDS in 124.7KB. Conflict-free layouts:
//     Wl[4][192][32] f32 : 8 o4-lanes span banks 0..31; b-lanes broadcast.
//     xgb[.][16][68] bf16: 8 b-lanes at 34b%32 = distinct even banks.
// ---------------------------------------------------------------------------
__global__ __launch_bounds__(512) void final_apply3(const float* __restrict__ X,
                                                    const float* __restrict__ E,
                                                    const float* __restrict__ G1,
                                                    const float* __restrict__ G2,
                                                    const float* __restrict__ wp,
                                                    const float* __restrict__ bp,
                                                    float* __restrict__ out) {
    const int ng = blockIdx.x;         // node group: nodes ng*4 .. ng*4+3
    const int oh = blockIdx.y;         // o-half: o0 = oh*32
    const int o0 = oh * 32;
    const int t  = threadIdx.x;
    __shared__ float Wl[4][192][32];       // 98304 B
    __shared__ u16   xgb[4][3][16][68];    // 26112 B (68-stride: bank-spread)
    __shared__ float esh[4][16];

    if (t < 64) esh[t >> 4][t & 15] = E[(ng * 4 + (t >> 4)) * DD + (t & 15)];

    // ---- stage xg (bf16): 3072 float4-chunks, 6 per thread ----
#pragma unroll
    for (int l = 0; l < 6; ++l) {
        const int c = t + l * 512;
        const int k  = c >> 10;          // 0..2
        const int j  = (c >> 8) & 3;     // node-in-group
        const int b  = (c >> 4) & 15;
        const int i4 = c & 15;
        const int n_g = ng * 4 + j;
        float4 v;
        if (k == 0) {
            v = *(const float4*)(X + ((size_t)b * NN + n_g) * CC + i4 * 4);
        } else if (k == 1) {
            v = *(const float4*)(G1 + (size_t)n_g * BC + b * 64 + i4 * 4);
        } else {
            float4 g2 = *(const float4*)(G2 + (size_t)n_g * BC + b * 64 + i4 * 4);
            float4 x  = *(const float4*)(X + ((size_t)b * NN + n_g) * CC + i4 * 4);
            v = make_float4(2.f * g2.x - x.x, 2.f * g2.y - x.y,
                            2.f * g2.z - x.z, 2.f * g2.w - x.w);
        }
        u32 w0 = (u32)f2bf(v.x) | ((u32)f2bf(v.y) << 16);
        u32 w1 = (u32)f2bf(v.z) | ((u32)f2bf(v.w) << 16);
        *(uint2*)&xgb[j][k][b][i4 * 4] = make_uint2(w0, w1);  // 8B-aligned (136B rows)
    }
    __syncthreads();

    // ---- W-gen: 1536 (ki,o4) tasks, 3 per thread; wp read ONCE for 4 nodes ----
    float er[4][16];
#pragma unroll
    for (int j = 0; j < 4; ++j)
#pragma unroll
        for (int d = 0; d < DD; ++d) er[j][d] = esh[j][d];

    const float4* wp4 = (const float4*)wp;
#pragma unroll
    for (int l = 0; l < 3; ++l) {
        const int tk = t + l * 512;
        const int ki = tk >> 3;          // 0..191  (k*64+i)
        const int q  = tk & 7;           // o4 quarter within the 32-o half
        float4 a0 = make_float4(0.f, 0.f, 0.f, 0.f);
        float4 a1 = a0, a2 = a0, a3 = a0;
#pragma unroll
        for (int d = 0; d < DD; ++d) {
            float4 v = wp4[d * 3072 + ki * 16 + oh * 8 + q];
            a0.x += er[0][d] * v.x; a0.y += er[0][d] * v.y; a0.z += er[0][d] * v.z; a0.w += er[0][d] * v.w;
            a1.x += er[1][d] * v.x; a1.y += er[1][d] * v.y; a1.z += er[1][d] * v.z; a1.w += er[1][d] * v.w;
            a2.x += er[2][d] * v.x; a2.y += er[2][d] * v.y; a2.z += er[2][d] * v.z; a2.w += er[2][d] * v.w;
            a3.x += er[3][d] * v.x; a3.y += er[3][d] * v.y; a3.z += er[3][d] * v.z; a3.w += er[3][d] * v.w;
        }
        *(float4*)&Wl[0][ki][q * 4] = a0;
        *(float4*)&Wl[1][ki][q * 4] = a1;
        *(float4*)&Wl[2][ki][q * 4] = a2;
        *(float4*)&Wl[3][ki][q * 4] = a3;
    }
    __syncthreads();

    // ---- apply: thread -> (n = t>>7, b = (t>>3)&15, o4 = t&7); wave = one n ----
    const int o4 = t & 7;
    const int b  = (t >> 3) & 15;
    const int n  = t >> 7;
    const int n_g = ng * 4 + n;

    const float4* bp4 = (const float4*)bp;
    float4 acc = make_float4(0.f, 0.f, 0.f, 0.f);
#pragma unroll
    for (int d = 0; d < DD; ++d) {
        const float e = esh[n][d];       // LDS (runtime n) - wave-uniform broadcast
        float4 bv = bp4[d * 16 + oh * 8 + o4];
        acc.x += e * bv.x; acc.y += e * bv.y; acc.z += e * bv.z; acc.w += e * bv.w;
    }
#pragma unroll
    for (int k = 0; k < 3; ++k) {
#pragma unroll
        for (int i2 = 0; i2 < 32; ++i2) {   // 2 i's per iter (u32 = 2 bf16)
            const u32 xu = *(const u32*)&xgb[n][k][b][i2 * 2];
            const float x0 = bf2f((u16)(xu & 0xffffu));
            const float x1 = bf2f((u16)(xu >> 16));
            const float4 w0 = *(const float4*)&Wl[n][k * 64 + i2 * 2][o4 * 4];
            const float4 w1 = *(const float4*)&Wl[n][k * 64 + i2 * 2 + 1][o4 * 4];
            acc.x += x0 * w0.x + x1 * w1.x;
            acc.y += x0 * w0.y + x1 * w1.y;
            acc.z += x0 * w0.z + x1 * w1.z;
            acc.w += x0 * w0.w + x1 * w1.w;
        }
    }
    *(float4*)(out + ((size_t)b * NN + n_g) * OO + o0 + o4 * 4) = acc;
}

// ---------------------------------------------------------------------------
extern "C" void kernel_launch(void* const* d_in, const int* in_sizes, int n_in,
                              void* d_out, int out_size, void* d_ws, size_t ws_size,
                              hipStream_t stream) {
    const float* X  = (const float*)d_in[0];   // [16,4096,64]
    const float* E  = (const float*)d_in[1];   // [4096,16]
    const float* wp = (const float*)d_in[3];   // [16,3,64,64]
    const float* bp = (const float*)d_in[4];   // [16,64]
    float* out = (float*)d_out;                // [16,4096,64]

    // ws layout (128 MB):
    u16* Ah   = (u16*)d_ws;                        // 32 MB
    u16* Al   = Ah   + (size_t)NN * NN;            // 32 MB
    u16* Xth  = Al   + (size_t)NN * NN;            //  8 MB
    u16* Xtl  = Xth  + (size_t)BC * NN;            //  8 MB
    u16* G1th = Xtl  + (size_t)BC * NN;            //  8 MB
    u16* G1tl = G1th + (size_t)BC * NN;            //  8 MB
    float* G1f = (float*)(G1tl + (size_t)BC * NN); // 16 MB (= gemm1 P0 slot)
    float* P1  = G1f + (size_t)NN * BC;            // 16 MB (shared partial slot)
    float* G2f = (float*)Xth;                      // overlay: Xt dead after gemm1
                                                   //   (= gemm2 P0 slot, 16 MB)

    softmax_adj<<<NN, 256, 0, stream>>>(E, Ah, Al);
    pack_xt<<<dim3(NN / 64, BB), 256, 0, stream>>>(X, Xth, Xtl);
    // GEMM1: G1 = A @ Xt^T  (K-split partials, then reduce + transpose-split)
    gemm_ks<<<512, 256, 0, stream>>>(Ah, Al, Xth, Xtl, G1f, P1);
    reduce_t<<<dim3(NN / 64, BC / 64), 256, 0, stream>>>(G1f, P1, G1th, G1tl);
    // GEMM2: G2 = A @ G1t^T
    gemm_ks<<<512, 256, 0, stream>>>(Ah, Al, G1th, G1tl, G2f, P1);
    reduce_lin<<<(NN * BC / 4) / 256, 256, 0, stream>>>(G2f, P1);
    final_apply3<<<dim3(NN / 4, 2), 512, 0, stream>>>(X, E, G1f, G2f, wp, bp, out);
}